// Round 7
// baseline (254.811 us; speedup 1.0000x reference)
//
#include <hip/hip_runtime.h>
#include <stdint.h>

// No implicit FMA contraction: the JAX eager reference has none across ops;
// where XLA fuses we write fmaf() explicitly.
#pragma clang fp contract(off)

#define PDIM 162
#define NW   (2*PDIM*PDIM*3)   // 157464 words, 1.26 MB per bitboard
#define OD   160
#define OD2  (160*160)
#define OD3  (160*160*160)
#define NOUT (2*OD3)
#define PZ   105               // LDS pitch per lz in u64 (105 % 8 == 1 -> Dbank=4)
#define LIDX(lz,ly) ((lz)*PZ + (ly)*3)
#define BTHR 512

// ---------------- threefry2x32, JAX partitionable scheme --------------------
__device__ __forceinline__ uint32_t rotl32(uint32_t x, uint32_t r) {
  return (x << r) | (x >> (32u - r));
}

__device__ __forceinline__ uint32_t threefry_bits(uint32_t idx) {
  const uint32_t ks0 = 0u, ks1 = 42u, ks2 = 0x1BD11BDAu ^ 0u ^ 42u;
  uint32_t x0 = 0u + ks0;
  uint32_t x1 = idx + ks1;
#define TFR(r) { x0 += x1; x1 = rotl32(x1, (r)); x1 ^= x0; }
  TFR(13u) TFR(15u) TFR(26u) TFR(6u)
  x0 += ks1; x1 += ks2 + 1u;
  TFR(17u) TFR(29u) TFR(16u) TFR(24u)
  x0 += ks2; x1 += ks0 + 2u;
  TFR(13u) TFR(15u) TFR(26u) TFR(6u)
  x0 += ks0; x1 += ks1 + 3u;
  TFR(17u) TFR(29u) TFR(16u) TFR(24u)
  x0 += ks1; x1 += ks2 + 4u;
  TFR(13u) TFR(15u) TFR(26u) TFR(6u)
  x0 += ks2; x1 += ks0 + 5u;
#undef TFR
  return x0 ^ x1;
}

// ------------- XLA-CPU (Cephes) float32 log replication ---------------------
__device__ __forceinline__ float xla_logf(float xin) {
  uint32_t bits = __float_as_uint(xin);
  float e = (float)((int)(bits >> 23) - 126);
  float x = __uint_as_float((bits & 0x007fffffu) | 0x3f000000u);
  const float SQRTHF = 0.707106781186547524f;
  bool lt = (x < SQRTHF);
  float tmp = lt ? x : 0.0f;
  e = e - (lt ? 1.0f : 0.0f);
  x = x - 1.0f;
  x = x + tmp;
  float z = x * x;
  float y = 7.0376836292e-2f;
  y = fmaf(y, x, -1.1514610310e-1f);
  y = fmaf(y, x,  1.1676998740e-1f);
  y = fmaf(y, x, -1.2420140846e-1f);
  y = fmaf(y, x,  1.4249322787e-1f);
  y = fmaf(y, x, -1.6668057665e-1f);
  y = fmaf(y, x,  2.0000714765e-1f);
  y = fmaf(y, x, -2.4999993993e-1f);
  y = fmaf(y, x,  3.3333331174e-1f);
  y = y * x;
  y = y * z;
  y = fmaf(e, -2.12194440e-4f, y);
  y = fmaf(-0.5f, z, y);
  x = x + y;
  x = fmaf(e, 0.693359375f, x);
  return x;
}

__device__ __forceinline__ float xla_log1pf(float x) {
  float for_large = xla_logf(x + 1.0f);
  float for_small = fmaf(-0.5f, x, 1.0f) * x;
  return (fabsf(x) < 1e-4f) ? for_small : for_large;
}

// ---------------------------- binarize --------------------------------------
__global__ __launch_bounds__(256) void k_binarize(const float* __restrict__ in,
                                                  uint64_t* __restrict__ bits) {
  uint32_t t = blockIdx.x * 256u + threadIdx.x;
  uint32_t w = t >> 6, lane = t & 63u;
  if (w >= (uint32_t)NW) return;          // wave-uniform
  uint32_t row = w / 3u, wx = w - row * 3u;
  uint32_t n  = row / (uint32_t)(PDIM * PDIM);
  uint32_t rr = row - n * (uint32_t)(PDIM * PDIM);
  uint32_t z  = rr / (uint32_t)PDIM;
  uint32_t y  = rr - z * (uint32_t)PDIM;
  uint32_t x  = wx * 64u + lane;
  bool pred = false;
  // pad voxels are provably 0: |0.33*noise| <= 6.08 < 18.42 = |log alpha(0)|
  if ((z - 1u) < 160u && (y - 1u) < 160u && (x - 1u) < 160u) {
    float v = in[((n * 160u + (z - 1u)) * 160u + (y - 1u)) * 160u + (x - 1u)];
    uint32_t i = row * 162u + x;          // flat padded index for RNG
    uint32_t b = threefry_bits(i);
    float f  = __uint_as_float((b >> 9) | 0x3f800000u) - 1.0f;
    float uu = fmaxf(1e-8f, f + 1e-8f);
    float la = xla_logf((v + 1e-8f) / ((1.0f - v) + 1e-8f));
    float noise = xla_logf(uu) - xla_log1pf(-uu);
    float zs = la + noise * 0.33f;
    pred = (zs > 1.1920928955078125e-7f); // logistic>0.5 iff z>2^-23
  }
  uint64_t m = __ballot(pred);
  if (lane == 0) bits[w] = m;
}

// ---------------- per-word neighborhood expansion from row triples ----------
#define NB(dz,dy,dx) ((dx)==-1 ? Lb[(dz)+1][(dy)+1] : ((dx)==1 ? Rb[(dz)+1][(dy)+1] : Vv[(dz)+1][(dy)+1]))

#define EXPAND_W(w_) \
  _Pragma("unroll") \
  for (int dz = 0; dz < 3; ++dz) \
    _Pragma("unroll") \
    for (int dy = 0; dy < 3; ++dy) { \
      uint64_t b = R[dz][dy][w_]; \
      uint64_t a = ((w_) > 0) ? R[dz][dy][(w_)-1] : 0ull; \
      uint64_t d = ((w_) < 2) ? R[dz][dy][(w_)+1] : 0ull; \
      Vv[dz][dy] = b; \
      Lb[dz][dy] = (b << 1) | (a >> 63); \
      Rb[dz][dy] = (b >> 1) | (d << 63); \
    }

// ---------------------------- iteration kernel ------------------------------
// One block: 16x16 (z,y) core x full 192-bit x, halo 8 -> 32x32 row tile.
// Thread task = one (z,y) row TRIPLE (all 3 words) -> 3x fewer LDS gathers.
__global__ __launch_bounds__(BTHR) void k_iter(const uint64_t* __restrict__ bin,
                                               uint64_t* __restrict__ bout,
                                               int zero_pads) {
  __shared__ uint64_t Bt[32 * PZ];
  __shared__ uint64_t Ge[32 * PZ];
  const int tid = threadIdx.x;
  const int bid = blockIdx.x;
  const int n  = bid / 100;
  const int rm = bid - n * 100;
  const int tz = rm / 10, ty = rm - tz * 10;
  const int gz0 = 1 + 16 * tz, gy0 = 1 + 16 * ty;   // both odd

  // Zero bout's pad rows (z or y in {0,161}) once per call (block 0, iter 1).
  if (zero_pads && bid == 0) {
    for (int j = tid; j < 1288; j += BTHR) {
      int nn, z, y;
      if (j < 648) { nn = j / 324; int r = j - nn * 324;
                     z = (r >= 162) ? 161 : 0; y = (r >= 162) ? r - 162 : r; }
      else { int j2 = j - 648; nn = j2 / 320; int r = j2 - nn * 320;
             y = (r >= 160) ? 161 : 0; z = 1 + ((r >= 160) ? r - 160 : r); }
      uint64_t* p = bout + (((nn * 162 + z) * 162) + y) * 3;
      p[0] = 0; p[1] = 0; p[2] = 0;
    }
  }

  // ---- load tile + halo 8 (w fastest -> coalesced global reads) ----
  for (int ti = tid; ti < 32 * 32 * 3; ti += BTHR) {
    int lz = ti / 96, rem = ti - lz * 96, ly = rem / 3, w = rem - ly * 3;
    int z = gz0 - 8 + lz, y = gy0 - 8 + ly;
    uint64_t v = 0;
    if ((unsigned)z < 162u && (unsigned)y < 162u)
      v = bin[((n * 162 + z) * 162 + y) * 3 + w];
    Bt[LIDX(lz, ly) + w] = v;
  }
  __syncthreads();

  // ---- ge2 (C26>=2) on halo 7; lanes stride lz (Dbank=18 -> 2-way, free) ---
  for (int ti = tid; ti < 30 * 30; ti += BTHR) {
    int iz = ti % 30, iy = ti / 30;
    int lz = 1 + iz, ly = 1 + iy;
    int base = LIDX(lz, ly);
    uint64_t c0 = Bt[base], c1 = Bt[base + 1], c2w = Bt[base + 2];
    if ((c0 | c1 | c2w) == 0ull) { Ge[base] = 0; Ge[base+1] = 0; Ge[base+2] = 0; continue; }
    uint64_t R[3][3][3];
#pragma unroll
    for (int dz = 0; dz < 3; ++dz)
#pragma unroll
      for (int dy = 0; dy < 3; ++dy) {
        int rb = LIDX(lz + dz - 1, ly + dy - 1);
        R[dz][dy][0] = Bt[rb]; R[dz][dy][1] = Bt[rb + 1]; R[dz][dy][2] = Bt[rb + 2];
      }
    uint64_t res[3];
#pragma unroll
    for (int w = 0; w < 3; ++w) {
      uint64_t Vv[3][3], Lb[3][3], Rb[3][3];
      EXPAND_W(w)
      uint64_t s = 0, c = 0;
#define ACC(bb) { uint64_t _b = (bb); c |= s & _b; s |= _b; }
#pragma unroll
      for (int dz = -1; dz <= 1; ++dz)
#pragma unroll
        for (int dy = -1; dy <= 1; ++dy) {
          ACC(NB(dz,dy,-1)); ACC(NB(dz,dy,1));
          if (dz != 0 || dy != 0) ACC(NB(dz,dy,0));
        }
#undef ACC
      res[w] = c;
    }
    Ge[base] = res[0]; Ge[base + 1] = res[1]; Ge[base + 2] = res[2];
  }
  __syncthreads();

  // ---- 8 subfield passes, halo 7-k; lanes stride iz (Dlz=2 -> Dbank=4) ----
  const int PLZ[8] = {1,0,1,0,1,0,1,0};   // lz parity (xo=0 -> z even -> lz odd)
  const int PLY[8] = {1,1,0,0,1,1,0,0};   // ly parity
  for (int k = 0; k < 8; ++k) {
    const int h = 7 - k, cnt1 = 8 + h;
    const uint64_t xmask = (k < 4) ? 0x5555555555555555ull : 0xAAAAAAAAAAAAAAAAull;
    int s0 = 8 - h;
    const int slz = s0 + ((s0 ^ PLZ[k]) & 1);
    const int sly = s0 + ((s0 ^ PLY[k]) & 1);
    for (int ti = tid; ti < cnt1 * cnt1; ti += BTHR) {
      int iz = ti % cnt1, iy = ti / cnt1;
      int lz = slz + 2 * iz, ly = sly + 2 * iy;
      int base = LIDX(lz, ly);
      uint64_t center[3], active[3];
#pragma unroll
      for (int w = 0; w < 3; ++w) {
        center[w] = Bt[base + w];
        active[w] = center[w] & xmask & Ge[base + w];
      }
      if ((active[0] | active[1] | active[2]) == 0ull) continue;
      uint64_t R[3][3][3];
#pragma unroll
      for (int dz = 0; dz < 3; ++dz)
#pragma unroll
        for (int dy = 0; dy < 3; ++dy) {
          int rb = LIDX(lz + dz - 1, ly + dy - 1);
          R[dz][dy][0] = Bt[rb]; R[dz][dy][1] = Bt[rb + 1]; R[dz][dy][2] = Bt[rb + 2];
        }
#pragma unroll
      for (int w = 0; w < 3; ++w) {
        if (active[w] == 0ull) continue;
        uint64_t Vv[3][3], Lb[3][3], Rb[3][3];
        EXPAND_W(w)

        // C6 exact 3-bit counter over the 6 faces
        uint64_t on = 0, tw = 0, fo = 0;
#define C6ADD(b) { uint64_t _u = on & (b); on ^= (b); uint64_t _v = tw & _u; tw ^= _u; fo |= _v; }
        C6ADD(NB(-1,0,0)) C6ADD(NB(1,0,0)) C6ADD(NB(0,-1,0))
        C6ADD(NB(0,1,0))  C6ADD(NB(0,0,-1)) C6ADD(NB(0,0,1))
#undef C6ADD
        uint64_t c6eq5 = fo & on & ~tw;
        uint64_t c6le4 = ~(fo & (on | tw));

        // carry-save ==1 detectors over 18 then 26 neighbors
        uint64_t s = 0, c2 = 0;
#define CS(b) { uint64_t _b = (b); c2 |= s & _b; s |= _b; }
        CS(NB(-1,0,0)) CS(NB(1,0,0)) CS(NB(0,-1,0)) CS(NB(0,1,0)) CS(NB(0,0,-1)) CS(NB(0,0,1))
        CS(NB(-1,-1,0)) CS(NB(-1,1,0)) CS(NB(-1,0,-1)) CS(NB(-1,0,1))
        CS(NB(1,-1,0))  CS(NB(1,1,0))  CS(NB(1,0,-1))  CS(NB(1,0,1))
        CS(NB(0,-1,-1)) CS(NB(0,-1,1)) CS(NB(0,1,-1))  CS(NB(0,1,1))
        uint64_t e18 = s & ~c2;
        CS(NB(-1,-1,-1)) CS(NB(-1,-1,1)) CS(NB(-1,1,-1)) CS(NB(-1,1,1))
        CS(NB(1,-1,-1))  CS(NB(1,-1,1))  CS(NB(1,1,-1))  CS(NB(1,1,1))
        uint64_t e26 = s & ~c2;
#undef CS

        // B: corner set with its 6 octant face/edge cells all clear
        uint64_t badB = 0;
#pragma unroll
        for (int sz = -1; sz <= 1; sz += 2)
#pragma unroll
          for (int sy = -1; sy <= 1; sy += 2)
#pragma unroll
            for (int sx = -1; sx <= 1; sx += 2) {
              uint64_t oct = NB(sz,0,0) | NB(0,sy,0) | NB(0,0,sx)
                           | NB(sz,sy,0) | NB(sz,0,sx) | NB(0,sy,sx);
              badB |= NB(sz,sy,sx) & ~oct;
            }
        uint64_t b0ok = ~badB;

        // A: face clear with its full 4-cell in-plane ring set
        uint64_t badA = 0;
        badA |= ~NB(-1,0,0) & NB(-1,-1,0) & NB(-1,1,0) & NB(-1,0,-1) & NB(-1,0,1);
        badA |= ~NB( 1,0,0) & NB( 1,-1,0) & NB( 1,1,0) & NB( 1,0,-1) & NB( 1,0,1);
        badA |= ~NB(0,-1,0) & NB(-1,-1,0) & NB(1,-1,0) & NB(0,-1,-1) & NB(0,-1,1);
        badA |= ~NB(0, 1,0) & NB(-1, 1,0) & NB(1, 1,0) & NB(0, 1,-1) & NB(0, 1,1);
        badA |= ~NB(0,0,-1) & NB(-1,0,-1) & NB(1,0,-1) & NB(0,-1,-1) & NB(0,1,-1);
        badA |= ~NB(0,0, 1) & NB(-1,0, 1) & NB(1,0, 1) & NB(0,-1, 1) & NB(0,1, 1);
        uint64_t a0ok = ~badA;

        uint64_t simple = c6eq5 | e26 | (e18 & b0ok) | (c6le4 & a0ok & b0ok);
        uint64_t del = simple & active[w];
        if (del) Bt[base + w] = center[w] & ~del;
        // readers only consume non-updated-parity bits; tearing-safe (R5 arg)
      }
    }
    __syncthreads();
  }

  // ---- write core words back (disjoint across blocks) ----
  for (int ti = tid; ti < 16 * 16 * 3; ti += BTHR) {
    int iz = ti / 48, rem = ti - iz * 48, iy = rem / 3, w = rem - iy * 3;
    bout[((n * 162 + gz0 + iz) * 162 + (gy0 + iy)) * 3 + w] =
        Bt[LIDX(8 + iz, 8 + iy) + w];
  }
}

// ---------------------------- output ----------------------------------------
__global__ __launch_bounds__(256) void k_output(const uint64_t* __restrict__ bits,
                                                float4* __restrict__ out) {
  uint32_t t = blockIdx.x * 256u + threadIdx.x;
  if (t >= (uint32_t)(NOUT / 4)) return;
  uint32_t i = t * 4u;
  uint32_t n = i / (uint32_t)OD3;
  uint32_t r = i - n * (uint32_t)OD3;
  uint32_t z = r / (uint32_t)OD2; r -= z * (uint32_t)OD2;
  uint32_t y = r / (uint32_t)OD;
  uint32_t x = r - y * (uint32_t)OD;
  uint32_t row = (n * 162u + z + 1u) * 162u + (y + 1u);
  uint32_t bi = x + 1u;
  uint32_t wx = bi >> 6, sft = bi & 63u;
  uint64_t v = bits[row * 3u + wx] >> sft;
  if (sft > 60u) v |= bits[row * 3u + wx + 1u] << (64u - sft);
  out[t] = make_float4((float)(v & 1u), (float)((v >> 1) & 1u),
                       (float)((v >> 2) & 1u), (float)((v >> 3) & 1u));
}

// ---------------------------- launcher --------------------------------------
extern "C" void kernel_launch(void* const* d_in, const int* in_sizes, int n_in,
                              void* d_out, int out_size, void* d_ws, size_t ws_size,
                              hipStream_t stream) {
  const float* in = (const float*)d_in[0];
  float4* out = (float4*)d_out;
  uint64_t* A = (uint64_t*)d_ws;          // bitboard A
  uint64_t* B = A + NW;                   // bitboard B

  k_binarize<<<dim3((NW * 64 + 255) / 256), dim3(256), 0, stream>>>(in, A);
  k_iter<<<dim3(200), dim3(BTHR), 0, stream>>>(A, B, 1);  // iter 1 (+zero B pads)
  k_iter<<<dim3(200), dim3(BTHR), 0, stream>>>(B, A, 0);  // iter 2
  k_iter<<<dim3(200), dim3(BTHR), 0, stream>>>(A, B, 0);  // iter 3
  k_iter<<<dim3(200), dim3(BTHR), 0, stream>>>(B, A, 0);  // iter 4
  k_iter<<<dim3(200), dim3(BTHR), 0, stream>>>(A, B, 0);  // iter 5
  k_output<<<dim3((NOUT / 4 + 255) / 256), dim3(256), 0, stream>>>(B, out);
}